// Round 8
// baseline (251.929 us; speedup 1.0000x reference)
//
#include <hip/hip_runtime.h>
#include <stdint.h>

#define Mdim 4096
#define Kdim 4096
#define Ndim 4096

typedef __attribute__((ext_vector_type(4))) int v4i;
typedef __attribute__((ext_vector_type(16))) int v16i;

__device__ __forceinline__ void gload_lds16(const void* g, void* l) {
  __builtin_amdgcn_global_load_lds(
      (__attribute__((address_space(1))) void*)(uintptr_t)g,
      (__attribute__((address_space(3))) void*)(uint32_t)(uintptr_t)l,
      16, 0, 0);
}

// ---- fused pack, 512 threads (FROZEN from R7, just validated) --------------
// Blocks [0,256): y-strips (16 n-cols x full K), LDS transpose, register csy,
// no atomics/memset. Blocks [256,2304): x rows, 2/block, int4 in/out + rsx.
__global__ __launch_bounds__(512) void pack_fused_kernel(
    const int* __restrict__ x, const int* __restrict__ y,
    char* __restrict__ x8, char* __restrict__ yt, int* __restrict__ rsx,
    int* __restrict__ csy) {
  __shared__ int shm[512 * 5];  // y: [512][5]; x: [0..7] as red
  const int t = threadIdx.x;
  if (blockIdx.x < 256) {
    const int n0 = blockIdx.x * 16;
    const int n = t >> 5;         // 0..15
    const int kq = t & 31;        // 16-k run within chunk
    const int colw = n >> 2;      // LDS word column
    const int byi = (n & 3) * 8;  // byte select
    int bsum = 0;
#pragma unroll 1
    for (int c = 0; c < 8; ++c) {
      const int k0 = c * 512;
#pragma unroll
      for (int p = 0; p < 4; ++p) {
        const int r = (t >> 2) + p * 128;  // k row 0..511
        int4 v = *(const int4*)(y + (size_t)(k0 + r) * Ndim + n0 + (t & 3) * 4);
        int wd = (v.x & 0xff) | ((v.y & 0xff) << 8) | ((v.z & 0xff) << 16) |
                 (v.w << 24);
        shm[r * 5 + (t & 3)] = wd ^ 0x80808080;  // == (b-128)&0xff per byte
      }
      __syncthreads();
      int outw[4];
#pragma unroll
      for (int j = 0; j < 4; ++j) {
        int b[4];
#pragma unroll
        for (int jj = 0; jj < 4; ++jj) {
          const int word = shm[(kq * 16 + j * 4 + jj) * 5 + colw];
          b[jj] = (word >> byi) & 0xff;
          bsum += (int)(char)b[jj];
        }
        outw[j] = b[0] | (b[1] << 8) | (b[2] << 16) | (b[3] << 24);
      }
      *(int4*)(yt + (size_t)(n0 + n) * Kdim + k0 + kq * 16) =
          make_int4(outw[0], outw[1], outw[2], outw[3]);
      __syncthreads();
    }
    bsum += __shfl_xor(bsum, 1, 64);
    bsum += __shfl_xor(bsum, 2, 64);
    bsum += __shfl_xor(bsum, 4, 64);
    bsum += __shfl_xor(bsum, 8, 64);
    bsum += __shfl_xor(bsum, 16, 64);
    if (kq == 0) csy[n0 + n] = bsum;
  } else {
    const int rowp = (int)(blockIdx.x - 256) * 2;
    const int h = t >> 8;
    const int tt = t & 255;
    const int row = rowp + h;
    const int4* src = (const int4*)(x + (size_t)row * Kdim);
    int4* dst = (int4*)(x8 + (size_t)row * Kdim);
    int sum = 0;
    int wd[4];
#pragma unroll
    for (int i = 0; i < 4; ++i) {
      int4 v = src[tt * 4 + i];  // contiguous 64B/lane (matches int4 store)
      sum += v.x + v.y + v.z + v.w;
      wd[i] = (v.x & 0xff) | ((v.y & 0xff) << 8) | ((v.z & 0xff) << 16) |
              (v.w << 24);
    }
    dst[tt] = make_int4(wd[0], wd[1], wd[2], wd[3]);
#pragma unroll
    for (int o = 32; o > 0; o >>= 1) sum += __shfl_down(sum, o, 64);
    if ((t & 63) == 0) shm[t >> 6] = sum;  // red[0..7]
    __syncthreads();
    if (t == 0) rsx[rowp] = shm[0] + shm[1] + shm[2] + shm[3];
    if (t == 256) rsx[rowp + 1] = shm[4] + shm[5] + shm[6] + shm[7];
  }
}

// ---- i8 GEMM: C = 7.5e-4*(A8 @ B8^T - 32*rsx[m] + 66*csy[n] - 2112*K) ------
// OCCUPANCY RESTRUCTURE: tile 128x256, 256 thr / 4 waves, 3 x 24KB LDS bufs
// (72KB) -> TWO independent blocks per CU (was 1 block, 8 waves, lockstep).
// Every prior schedule variant (76-91us band) shared 1-block/CU lockstep:
// each barrier stalled the whole CU with nothing to fill it. With 2 barrier
// groups per CU, one block's MFMA covers the other's barrier/load stalls
// (m114 mechanism: implicit wave-level overlap is what source pipelining
// can't buy). Per-wave work per tile unchanged (16 MFMA, 12 ds_read_b128);
// simple 2-barrier/tile counted-vmcnt loop (6 loads/stage, WAITV(12)).
__global__ __launch_bounds__(256, 2) void gemm_i8_kernel(
    const char* __restrict__ A, const char* __restrict__ B,
    const int* __restrict__ rsx, const int* __restrict__ csy,
    float* __restrict__ out) {
  __shared__ __align__(16) char lds[3 * 24576];  // buf: [As 8K | Bs 16K] x3
  const int t = threadIdx.x;
  const int l = t & 63;
  const int w = t >> 6;      // 0..3
  const int warow = w >> 1;  // 0..1 (x64 rows)
  const int wbcol = w & 1;   // 0..1 (x128 cols)
  const int bm = blockIdx.y * 128;
  const int bn = blockIdx.x * 256;

  v16i acc[2][4];
#pragma unroll
  for (int i = 0; i < 2; ++i)
#pragma unroll
    for (int j = 0; j < 4; ++j)
#pragma unroll
      for (int q = 0; q < 16; ++q) acc[i][j][q] = 0;

  // Staging: thread t covers row (t>>2) + 64*i, 16B slot (t&3); slot holds
  // global chunk (t&3)^((row>>1)&3); key (t>>3)&3 invariant under +64 rows.
  const int srow = t >> 2;  // 0..63
  const int cswz = ((t & 3) ^ ((t >> 3) & 3)) * 16;
  const char* gA = A + (size_t)(bm + srow) * Kdim + cswz;
  const char* gB = B + (size_t)(bn + srow) * Kdim + cswz;

// Stage one tile: A 8KB (2 passes) + B 16KB (4 passes), 6 loads/thread.
#define STAGE(buf_off, koff)                                                  \
  do {                                                                        \
    _Pragma("unroll") for (int i = 0; i < 2; ++i)                             \
        gload_lds16(gA + (koff) + (size_t)i * 64 * Kdim,                      \
                    lds + (buf_off) + i * 4096 + t * 16);                     \
    _Pragma("unroll") for (int i = 0; i < 4; ++i)                             \
        gload_lds16(gB + (koff) + (size_t)i * 64 * Kdim,                      \
                    lds + (buf_off) + 8192 + i * 4096 + t * 16);              \
  } while (0)

  const int arow = warow * 64 + (l & 31);   // A rows 0..127 via +i*32
  const int brow = wbcol * 128 + (l & 31);  // B rows 0..255 via +j*32
  const int lhalf = l >> 5;
  const int lkey = (l >> 1) & 3;  // == (frag_row>>1)&3 for all frag rows

#define MFMA(a, b, c) __builtin_amdgcn_mfma_i32_32x32x32_i8(a, b, c, 0, 0, 0)
#define SETP(n) __builtin_amdgcn_s_setprio(n)
#define BAR()                                                                 \
  do {                                                                        \
    asm volatile("" ::: "memory");                                            \
    __builtin_amdgcn_s_barrier();                                             \
    asm volatile("" ::: "memory");                                            \
  } while (0)
#define WAITV(n) asm volatile("s_waitcnt vmcnt(" #n ")" ::: "memory")

#define COMPUTE(buf_off)                                                      \
  do {                                                                        \
    const char* As = lds + (buf_off);                                         \
    const char* Bs = lds + (buf_off) + 8192;                                  \
    SETP(1);                                                                  \
    _Pragma("unroll") for (int ks = 0; ks < 2; ++ks) {                        \
      const int slot = ((ks * 2 + lhalf) ^ lkey) * 16;                        \
      v4i a[2], b[4];                                                         \
      _Pragma("unroll") for (int i = 0; i < 2; ++i)                           \
          a[i] = *(const v4i*)(As + (arow + i * 32) * 64 + slot);             \
      _Pragma("unroll") for (int j = 0; j < 4; ++j)                           \
          b[j] = *(const v4i*)(Bs + (brow + j * 32) * 64 + slot);             \
      _Pragma("unroll") for (int i = 0; i < 2; ++i)                           \
          _Pragma("unroll") for (int j = 0; j < 4; ++j)                       \
              acc[i][j] = MFMA(a[i], b[j], acc[i][j]);                        \
    }                                                                         \
    SETP(0);                                                                  \
  } while (0)

  // Prologue: stage tiles 0,1,2 (18 loads in flight); WAITV(12) certifies
  // tile 0 (t1,t2 stay flying); barrier publishes.
  STAGE(0, 0);
  STAGE(24576, 64);
  STAGE(49152, 128);
  WAITV(12);
  BAR();

  // Steady state per tile kt (buf kt%3): COMPUTE(cur); BAR (readers done);
  // STAGE(cur <- tile kt+3); WAITV(12) certifies tile kt+1; BAR.
#pragma unroll 1
  for (int kt = 0; kt < 60; kt += 3) {
    COMPUTE(0);
    BAR();
    STAGE(0, (kt + 3) * 64);
    WAITV(12);
    BAR();
    COMPUTE(24576);
    BAR();
    STAGE(24576, (kt + 4) * 64);
    WAITV(12);
    BAR();
    COMPUTE(49152);
    BAR();
    STAGE(49152, (kt + 5) * 64);
    WAITV(12);
    BAR();
  }
  // kt=60: stage tile 63 -> buf0 (readers finished at the BAR after COMPUTE).
  COMPUTE(0);
  BAR();
  STAGE(0, 63 * 64);
  WAITV(12);  // certifies t61
  BAR();
  // kt=61
  COMPUTE(24576);
  BAR();
  WAITV(6);  // certifies t62
  BAR();
  // kt=62
  COMPUTE(49152);
  BAR();
  WAITV(0);  // certifies t63
  BAR();
  // kt=63
  COMPUTE(0);

  // Epilogue. C/D 32x32 layout: col=lane&31, row=(r&3)+8*(r>>2)+4*(lane>>5)
  const int col = l & 31;
#pragma unroll
  for (int i = 0; i < 2; ++i) {
    const int gm0 = bm + warow * 64 + i * 32;
#pragma unroll
    for (int j = 0; j < 4; ++j) {
      const int gn = bn + wbcol * 128 + j * 32 + col;
      const int cs = 66 * csy[gn] - 8650752;  // -2112*4096
#pragma unroll
      for (int r = 0; r < 16; ++r) {
        const int row = (r & 3) + 8 * (r >> 2) + 4 * lhalf;
        const int gm = gm0 + row;
        const int val = acc[i][j][r] - 32 * rsx[gm] + cs;
        out[(size_t)gm * Ndim + gn] = 7.5e-4f * (float)val;
      }
    }
  }
#undef STAGE
#undef COMPUTE
#undef MFMA
#undef SETP
#undef BAR
#undef WAITV
}

extern "C" void kernel_launch(void* const* d_in, const int* in_sizes, int n_in,
                              void* d_out, int out_size, void* d_ws, size_t ws_size,
                              hipStream_t stream) {
  (void)in_sizes; (void)n_in; (void)out_size; (void)ws_size;
  const int* x = (const int*)d_in[0];
  const int* y = (const int*)d_in[1];
  float* out = (float*)d_out;
  char* ws = (char*)d_ws;
  char* x8 = ws;                                          // 16 MB
  char* yt = ws + (size_t)Mdim * Kdim;                    // 16 MB (row-major)
  int* rsx = (int*)(ws + (size_t)Mdim * Kdim + (size_t)Kdim * Ndim);
  int* csy = rsx + Mdim;

  pack_fused_kernel<<<256 + Mdim / 2, 512, 0, stream>>>(x, y, x8, yt, rsx, csy);
  gemm_i8_kernel<<<dim3(Ndim / 256, Mdim / 128), 256, 0, stream>>>(x8, yt, rsx,
                                                                   csy, out);
}

// Round 9
// 236.380 us; speedup vs baseline: 1.0658x; 1.0658x over previous
//
#include <hip/hip_runtime.h>
#include <stdint.h>

#define Mdim 4096
#define Kdim 4096
#define Ndim 4096

typedef __attribute__((ext_vector_type(4))) int v4i;

__device__ __forceinline__ void gload_lds16(const void* g, void* l) {
  __builtin_amdgcn_global_load_lds(
      (__attribute__((address_space(1))) void*)(uintptr_t)g,
      (__attribute__((address_space(3))) void*)(uint32_t)(uintptr_t)l,
      16, 0, 0);
}

// ---- fused pack, 512 threads (FROZEN from R7, validated twice) -------------
__global__ __launch_bounds__(512) void pack_fused_kernel(
    const int* __restrict__ x, const int* __restrict__ y,
    char* __restrict__ x8, char* __restrict__ yt, int* __restrict__ rsx,
    int* __restrict__ csy) {
  __shared__ int shm[512 * 5];
  const int t = threadIdx.x;
  if (blockIdx.x < 256) {
    const int n0 = blockIdx.x * 16;
    const int n = t >> 5;
    const int kq = t & 31;
    const int colw = n >> 2;
    const int byi = (n & 3) * 8;
    int bsum = 0;
#pragma unroll 1
    for (int c = 0; c < 8; ++c) {
      const int k0 = c * 512;
#pragma unroll
      for (int p = 0; p < 4; ++p) {
        const int r = (t >> 2) + p * 128;
        int4 v = *(const int4*)(y + (size_t)(k0 + r) * Ndim + n0 + (t & 3) * 4);
        int wd = (v.x & 0xff) | ((v.y & 0xff) << 8) | ((v.z & 0xff) << 16) |
                 (v.w << 24);
        shm[r * 5 + (t & 3)] = wd ^ 0x80808080;  // (b-128)&0xff per byte
      }
      __syncthreads();
      int outw[4];
#pragma unroll
      for (int j = 0; j < 4; ++j) {
        int b[4];
#pragma unroll
        for (int jj = 0; jj < 4; ++jj) {
          const int word = shm[(kq * 16 + j * 4 + jj) * 5 + colw];
          b[jj] = (word >> byi) & 0xff;
          bsum += (int)(char)b[jj];
        }
        outw[j] = b[0] | (b[1] << 8) | (b[2] << 16) | (b[3] << 24);
      }
      *(int4*)(yt + (size_t)(n0 + n) * Kdim + k0 + kq * 16) =
          make_int4(outw[0], outw[1], outw[2], outw[3]);
      __syncthreads();
    }
    bsum += __shfl_xor(bsum, 1, 64);
    bsum += __shfl_xor(bsum, 2, 64);
    bsum += __shfl_xor(bsum, 4, 64);
    bsum += __shfl_xor(bsum, 8, 64);
    bsum += __shfl_xor(bsum, 16, 64);
    if (kq == 0) csy[n0 + n] = bsum;
  } else {
    const int rowp = (int)(blockIdx.x - 256) * 2;
    const int h = t >> 8;
    const int tt = t & 255;
    const int row = rowp + h;
    const int4* src = (const int4*)(x + (size_t)row * Kdim);
    int4* dst = (int4*)(x8 + (size_t)row * Kdim);
    int sum = 0;
    int wd[4];
#pragma unroll
    for (int i = 0; i < 4; ++i) {
      int4 v = src[tt * 4 + i];
      sum += v.x + v.y + v.z + v.w;
      wd[i] = (v.x & 0xff) | ((v.y & 0xff) << 8) | ((v.z & 0xff) << 16) |
              (v.w << 24);
    }
    dst[tt] = make_int4(wd[0], wd[1], wd[2], wd[3]);
#pragma unroll
    for (int o = 32; o > 0; o >>= 1) sum += __shfl_down(sum, o, 64);
    if ((t & 63) == 0) shm[t >> 6] = sum;
    __syncthreads();
    if (t == 0) rsx[rowp] = shm[0] + shm[1] + shm[2] + shm[3];
    if (t == 256) rsx[rowp + 1] = shm[4] + shm[5] + shm[6] + shm[7];
  }
}

// ---- i8 GEMM: C = 7.5e-4*(A8 @ B8^T - 32*rsx[m] + 66*csy[n] - 2112*K) ------
// m201-template port, 16x16x64 fragments (conflict-free LDS geometry).
// 512 thr / 8 waves; tile 256x256; BK=128B; per-wave 64x128 = 4m x 8n accs
// of 16x16 (128 AGPR). LDS: 2 bufs x [A 32K | B 32K] = 128KB, rows 128B.
// Swizzle (both-sides, rule #21): LDS slot = chunk ^ (row&7); staging source
// pre-swizzled: thread t loads global chunk (t&7)^((t>>3)&7) of row t>>3.
// Frag reads: lane row = l&15 -> 16 rows x 8 slots^(l&7) = full 32-bank
// spread at 2-way (free). (32x32 frags had a 4-way geometric floor: the
// 6.29M-cycle SQ_LDS_BANK_CONFLICT constant across all prior rounds.)
// Per K-tile, 4 quadrant-phases of {ds_read B-pair (+A all in q0), 2 staging
// loads, BAR, lgkmcnt(0)+sched_barrier, setprio(1), 16 MFMA, setprio(0),
// BAR}. A-frags resident across the tile: 24 reads/tile/wave, zero redundancy.
// Staging order [A p0..3 | B p0,p2 | B p1,p3] makes counted waits legal:
//   W1 = vmcnt(4) at q1 end: retires this tile's B p1,p3 (read in q2/q3);
//        4 newest (next tile's A p0..3) fly.
//   W3 = vmcnt(2) at q3 end: retires next tile's A + B p0,p2 (needed q0/q1);
//        2 newest (next tile's B p1,p3) fly.  Never vmcnt(0) in steady state.
__global__ __launch_bounds__(512, 1) void gemm_i8_kernel(
    const char* __restrict__ A, const char* __restrict__ B,
    const int* __restrict__ rsx, const int* __restrict__ csy,
    float* __restrict__ out) {
  __shared__ __align__(16) char lds[2 * 65536];
  const int t = threadIdx.x;
  const int l = t & 63;
  const int w = t >> 6;      // 0..7
  const int warow = w >> 1;  // 0..3: 64-row A slice
  const int wbcol = w & 1;   // 0..1: 128-col B slice
  const int bm = blockIdx.y * 256;
  const int bn = blockIdx.x * 256;

  v4i acc[4][8];
#pragma unroll
  for (int m = 0; m < 4; ++m)
#pragma unroll
    for (int n = 0; n < 8; ++n)
#pragma unroll
      for (int q = 0; q < 4; ++q) acc[m][n][q] = 0;

  // Staging: thread t -> pass rows p*64 + (t>>3), slot t&7 holds global
  // chunk (t&7)^((t>>3)&7) (pre-swizzled source; (row&7) invariant under +64).
  const int srow = t >> 3;  // 0..63
  const int cswz = ((t & 7) ^ (srow & 7)) * 16;
  const char* gA = A + (size_t)(bm + srow) * Kdim + cswz;
  const char* gB = B + (size_t)(bn + srow) * Kdim + cswz;

// One staging load: part 0=A,1=B; pass p covers rows p*64..p*64+63.
#define STG(sbo, koff, part, pass)                                            \
  gload_lds16(((part) ? gB : gA) + (koff) + (size_t)(pass) * 64 * Kdim,       \
              lds + (sbo) + (part) * 32768 + (pass) * 8192 + t * 16)

  // Fragment read addressing (16x16x64): lane -> row l&15, k-quarter l>>4.
  // addr = base + row*128 + ((ks*4 + (l>>4)) ^ (l&7))*16 ; row&7 == l&7.
  const int lq = l >> 4;
  const int lk = l & 7;
  const int sl0 = (((0 + lq) ^ lk) << 4);  // ks=0 swizzled slot byte
  const int sl1 = (((4 + lq) ^ lk) << 4);  // ks=1
  const int abase = (warow * 64 + (l & 15)) * 128;            // + m*2048
  const int bbase = 32768 + (wbcol * 128 + (l & 15)) * 128;   // + n*2048

  v4i fa0[4], fa1[4];  // A-frags (ks0/ks1 x m), resident per tile

#define MFMA(a, b, c) __builtin_amdgcn_mfma_i32_16x16x64_i8(a, b, c, 0, 0, 0)
#define SETP(n) __builtin_amdgcn_s_setprio(n)
#define FENCE() __builtin_amdgcn_sched_barrier(0)
#define LGKM0() asm volatile("s_waitcnt lgkmcnt(0)" ::: "memory")
#define BAR()                                                                 \
  do {                                                                        \
    asm volatile("" ::: "memory");                                            \
    __builtin_amdgcn_s_barrier();                                             \
    asm volatile("" ::: "memory");                                            \
  } while (0)
#define WAITV(n) asm volatile("s_waitcnt vmcnt(" #n ")" ::: "memory")

// One phase: B-pair reads (+optional A), 2 staging loads, BAR, lgkm drain,
// 16 MFMA, optional tail wait, BAR.
#define PHASE(bo, n0_, RDA, sbo, koff, DOSTAGE, SP, SQ, SR, SS, TAILW)        \
  do {                                                                        \
    if (RDA) {                                                                \
      _Pragma("unroll") for (int m = 0; m < 4; ++m) {                         \
        fa0[m] = *(const v4i*)(lds + (bo) + abase + m * 2048 + sl0);          \
        fa1[m] = *(const v4i*)(lds + (bo) + abase + m * 2048 + sl1);          \
      }                                                                       \
    }                                                                         \
    {                                                                         \
      v4i b00 = *(const v4i*)(lds + (bo) + bbase + (n0_)*2048 + sl0);         \
      v4i b01 = *(const v4i*)(lds + (bo) + bbase + ((n0_) + 1) * 2048 + sl0); \
      v4i b10 = *(const v4i*)(lds + (bo) + bbase + (n0_)*2048 + sl1);         \
      v4i b11 = *(const v4i*)(lds + (bo) + bbase + ((n0_) + 1) * 2048 + sl1); \
      if (DOSTAGE) {                                                          \
        STG(sbo, koff, SP, SQ);                                               \
        STG(sbo, koff, SR, SS);                                               \
      }                                                                       \
      BAR();                                                                  \
      LGKM0();                                                                \
      FENCE();                                                                \
      SETP(1);                                                                \
      _Pragma("unroll") for (int m = 0; m < 4; ++m) {                         \
        acc[m][(n0_)] = MFMA(fa0[m], b00, acc[m][(n0_)]);                     \
        acc[m][(n0_)] = MFMA(fa1[m], b10, acc[m][(n0_)]);                     \
        acc[m][(n0_) + 1] = MFMA(fa0[m], b01, acc[m][(n0_) + 1]);             \
        acc[m][(n0_) + 1] = MFMA(fa1[m], b11, acc[m][(n0_) + 1]);             \
      }                                                                       \
      SETP(0);                                                                \
      FENCE();                                                                \
      TAILW;                                                                  \
      BAR();                                                                  \
    }                                                                         \
  } while (0)

// Tile = 4 phases. Staging schedule: q0->A p0,p1; q1->A p2,p3; q2->B p0,p2;
// q3->B p1,p3. Waits: W1 after q1 MFMAs, W3 after q3 MFMAs.
#define TILE(bo, sbo, koff, DOSTAGE, W1, W3)                                  \
  do {                                                                        \
    PHASE(bo, 0, 1, sbo, koff, DOSTAGE, 0, 0, 0, 1, (void)0);                 \
    PHASE(bo, 2, 0, sbo, koff, DOSTAGE, 0, 2, 0, 3, W1);                      \
    PHASE(bo, 4, 0, sbo, koff, DOSTAGE, 1, 0, 1, 2, (void)0);                 \
    PHASE(bo, 6, 0, sbo, koff, DOSTAGE, 1, 1, 1, 3, W3);                      \
  } while (0)

  // Prologue: stage tile 0 fully; one-time drain.
#pragma unroll
  for (int p = 0; p < 4; ++p) STG(0, 0, 0, p);
#pragma unroll
  for (int p = 0; p < 4; ++p) STG(0, 0, 1, p);
  WAITV(0);
  BAR();

  // 32 K-tiles; tile kt computes buf kt&1, stages kt+1 into buf (kt&1)^1.
#pragma unroll 1
  for (int kt = 0; kt < 30; kt += 2) {
    TILE(0, 65536, (kt + 1) * 128, 1, WAITV(4), WAITV(2));
    TILE(65536, 0, (kt + 2) * 128, 1, WAITV(4), WAITV(2));
  }
  TILE(0, 65536, 31 * 128, 1, WAITV(4), WAITV(2));  // kt=30, stages t31
  TILE(65536, 0, 0, 0, WAITV(0), (void)0);          // kt=31, drain at W1

  // Epilogue. 16x16 C/D layout: col = lane&15, row = (lane>>4)*4 + reg.
  const int col = l & 15;
  const int r4 = lq * 4;
#pragma unroll
  for (int m = 0; m < 4; ++m) {
    const int gm0 = bm + warow * 64 + m * 16 + r4;
    int rsv[4];
#pragma unroll
    for (int r = 0; r < 4; ++r) rsv[r] = 32 * rsx[gm0 + r];
#pragma unroll
    for (int n = 0; n < 8; ++n) {
      const int gn = bn + wbcol * 128 + n * 16 + col;
      const int cs = 66 * csy[gn] - 8650752;  // -2112*4096
#pragma unroll
      for (int r = 0; r < 4; ++r) {
        const int val = acc[m][n][r] - rsv[r] + cs;
        out[(size_t)(gm0 + r) * Ndim + gn] = 7.5e-4f * (float)val;
      }
    }
  }
#undef STG
#undef PHASE
#undef TILE
#undef MFMA
#undef SETP
#undef FENCE
#undef LGKM0
#undef BAR
#undef WAITV
}

extern "C" void kernel_launch(void* const* d_in, const int* in_sizes, int n_in,
                              void* d_out, int out_size, void* d_ws, size_t ws_size,
                              hipStream_t stream) {
  (void)in_sizes; (void)n_in; (void)out_size; (void)ws_size;
  const int* x = (const int*)d_in[0];
  const int* y = (const int*)d_in[1];
  float* out = (float*)d_out;
  char* ws = (char*)d_ws;
  char* x8 = ws;                                          // 16 MB
  char* yt = ws + (size_t)Mdim * Kdim;                    // 16 MB (row-major)
  int* rsx = (int*)(ws + (size_t)Mdim * Kdim + (size_t)Kdim * Ndim);
  int* csy = rsx + Mdim;

  pack_fused_kernel<<<256 + Mdim / 2, 512, 0, stream>>>(x, y, x8, yt, rsx, csy);
  gemm_i8_kernel<<<dim3(Ndim / 256, Mdim / 256), 512, 0, stream>>>(x8, yt, rsx,
                                                                   csy, out);
}